// Round 1
// baseline (880.649 us; speedup 1.0000x reference)
//
#include <hip/hip_runtime.h>
#include <hip/hip_bf16.h>
#include <math.h>

#define NN 100000
#define NFEATC 256
#define NHIDC 128
#define NCLS 40
#define DEGC 16
#define NEDGE (NN*DEGC)
#define ALPHAC 0.2f
#define LPALPHA 0.5f

// ---------------------------------------------------------------------------
// Big GEMM: C[NN][128] = A1[NN][K1] @ B1[K1][128] + A2[NN][K2] @ B2[K2][128] (+bias)
// B matrices supplied in [K][128] (k-major) layout. 64-row x 128-col tile/block.
// ---------------------------------------------------------------------------
__global__ __launch_bounds__(256) void gemm128_dual(
    const float* __restrict__ A1, int K1, const float* __restrict__ B1,
    const float* __restrict__ A2, int K2, const float* __restrict__ B2,
    const float* __restrict__ bias, float* __restrict__ C)
{
    __shared__ float As[64][33];
    __shared__ float Bs[32][128];
    const int n0 = blockIdx.x * 64;
    const int tid = threadIdx.x;
    const int rg = tid >> 4;   // 0..15 (4 rows each)
    const int cg = tid & 15;   // 0..15 (8 cols each)
    float acc[4][8];
#pragma unroll
    for (int r = 0; r < 4; ++r)
#pragma unroll
        for (int c = 0; c < 8; ++c) acc[r][c] = 0.f;

    for (int src = 0; src < 2; ++src) {
        const float* __restrict__ A = src ? A2 : A1;
        const float* __restrict__ B = src ? B2 : B1;
        const int K = src ? K2 : K1;
        if (A == nullptr) continue;
        for (int k0 = 0; k0 < K; k0 += 32) {
            const int kt = (K - k0 < 32) ? (K - k0) : 32;
            // A tile: 64 rows x 32 k (zero-padded)
#pragma unroll
            for (int s = 0; s < 2; ++s) {
                int slot = tid + s * 256;           // float4 slot over 64x8
                int r = slot >> 3;
                int ko = (slot & 7) << 2;
                float4 v = make_float4(0.f, 0.f, 0.f, 0.f);
                int gr = n0 + r;
                if (gr < NN) {
                    if (ko + 4 <= kt) {
                        v = *(const float4*)(A + (size_t)gr * K + k0 + ko);
                    } else {
                        float tmp[4] = {0.f, 0.f, 0.f, 0.f};
                        for (int q = 0; q < 4; ++q)
                            if (ko + q < kt) tmp[q] = A[(size_t)gr * K + k0 + ko + q];
                        v = make_float4(tmp[0], tmp[1], tmp[2], tmp[3]);
                    }
                }
                As[r][ko + 0] = v.x; As[r][ko + 1] = v.y;
                As[r][ko + 2] = v.z; As[r][ko + 3] = v.w;
            }
            // B tile: 32 k x 128 m (zero-padded)
#pragma unroll
            for (int s = 0; s < 4; ++s) {
                int slot = tid + s * 256;           // float4 slot over 32x32
                int kr = slot >> 5;
                int mo = (slot & 31) << 2;
                float4 v = make_float4(0.f, 0.f, 0.f, 0.f);
                if (kr < kt) v = *(const float4*)(B + (size_t)(k0 + kr) * 128 + mo);
                *(float4*)&Bs[kr][mo] = v;
            }
            __syncthreads();
#pragma unroll
            for (int kk = 0; kk < 32; ++kk) {
                float a0 = As[rg * 4 + 0][kk];
                float a1 = As[rg * 4 + 1][kk];
                float a2 = As[rg * 4 + 2][kk];
                float a3 = As[rg * 4 + 3][kk];
                float4 b0 = *(const float4*)&Bs[kk][cg * 8];
                float4 b1 = *(const float4*)&Bs[kk][cg * 8 + 4];
                float bb[8] = {b0.x, b0.y, b0.z, b0.w, b1.x, b1.y, b1.z, b1.w};
#pragma unroll
                for (int c = 0; c < 8; ++c) {
                    acc[0][c] += a0 * bb[c];
                    acc[1][c] += a1 * bb[c];
                    acc[2][c] += a2 * bb[c];
                    acc[3][c] += a3 * bb[c];
                }
            }
            __syncthreads();
        }
    }
#pragma unroll
    for (int r = 0; r < 4; ++r) {
        int gr = n0 + rg * 4 + r;
        if (gr < NN) {
            float o[8];
#pragma unroll
            for (int c = 0; c < 8; ++c)
                o[c] = acc[r][c] + (bias ? bias[cg * 8 + c] : 0.f);
            *(float4*)(C + (size_t)gr * 128 + cg * 8)     = make_float4(o[0], o[1], o[2], o[3]);
            *(float4*)(C + (size_t)gr * 128 + cg * 8 + 4) = make_float4(o[4], o[5], o[6], o[7]);
        }
    }
}

// ---------------------------------------------------------------------------
// Small GEMM: M[NN][16] = A[NN][128] @ W[16][128]^T + bias.  16 rows/block.
// ---------------------------------------------------------------------------
__global__ __launch_bounds__(256) void gemm16(
    const float* __restrict__ A, const float* __restrict__ W,
    const float* __restrict__ bias, float* __restrict__ Mout)
{
    __shared__ float As[16][132];
    __shared__ float Wt[128][17];
    const int n0 = blockIdx.x * 16;
    const int tid = threadIdx.x;
#pragma unroll
    for (int s = 0; s < 8; ++s) {              // stage W transposed: 2048 elems
        int f = tid + s * 256;
        int m = f >> 7, k = f & 127;
        Wt[k][m] = W[f];
    }
#pragma unroll
    for (int s = 0; s < 2; ++s) {              // stage 16 A rows
        int slot = tid + s * 256;              // float4 slots over 16x32
        int r = slot >> 5, ko = (slot & 31) << 2;
        float4 v = *(const float4*)(A + (size_t)(n0 + r) * 128 + ko);
        *(float4*)&As[r][ko] = v;
    }
    __syncthreads();
    const int row = tid >> 4, m = tid & 15;
    float acc = bias[m];
#pragma unroll
    for (int k = 0; k < 128; ++k) acc += As[row][k] * Wt[k][m];
    Mout[(size_t)(n0 + row) * 16 + m] = acc;
}

// ---------------------------------------------------------------------------
// mini() second half: d2[i] = mean_e ||avg_i - m[col_e]||  (avg_i = mean of m[col])
// 16 nodes/block, 16 threads/node.
// ---------------------------------------------------------------------------
__global__ __launch_bounds__(256) void mini2_kernel(
    const float* __restrict__ Mm, const int* __restrict__ col,
    float* __restrict__ d2out)
{
    __shared__ float sm[16][16][17];
    __shared__ float av[16][16];
    const int node0 = blockIdx.x * 16;
    const int tid = threadIdx.x;
    const int g = tid >> 4, j = tid & 15;
    const int node = node0 + g;
    const int c = col[node * 16 + j];
#pragma unroll
    for (int s = 0; s < 4; ++s) {
        float4 v = *(const float4*)(Mm + (size_t)c * 16 + s * 4);
        sm[g][j][s * 4 + 0] = v.x; sm[g][j][s * 4 + 1] = v.y;
        sm[g][j][s * 4 + 2] = v.z; sm[g][j][s * 4 + 3] = v.w;
    }
    __syncthreads();
    float a = 0.f;
#pragma unroll
    for (int nb = 0; nb < 16; ++nb) a += sm[g][nb][j];
    av[g][j] = a * (1.f / 16.f);
    __syncthreads();
    float dd = 1e-12f;
#pragma unroll
    for (int d = 0; d < 16; ++d) {
        float t = av[g][d] - sm[g][j][d];
        dd += t * t;
    }
    float dist = sqrtf(dd);
#pragma unroll
    for (int off = 1; off < 16; off <<= 1) dist += __shfl_xor(dist, off, 64);
    if (j == 0) d2out[node] = dist * (1.f / 16.f);
}

// ---------------------------------------------------------------------------
// Aggregation: h[i] = aggr_i * (sum_c lpw[c]*deg[c]*hlin[c]) * deg[i] + (1-aggr_i)*hlin[i]
// 2 nodes/block, 128 threads/node (one per hidden dim).
// ---------------------------------------------------------------------------
__global__ __launch_bounds__(256) void agg_kernel(
    const float* __restrict__ hlin, const int* __restrict__ col,
    const float* __restrict__ lpw, const float* __restrict__ degree,
    const float* __restrict__ aggrv, const float aggrs,
    float* __restrict__ hout)
{
    __shared__ int cs[2][16];
    __shared__ float ss[2][16];
    const int g = threadIdx.x >> 7;
    const int j = threadIdx.x & 127;
    const int node = blockIdx.x * 2 + g;
    if (j < 16) {
        int c = col[node * 16 + j];
        cs[g][j] = c;
        ss[g][j] = lpw[c] * degree[c];
    }
    __syncthreads();
    float acc = 0.f;
#pragma unroll
    for (int t = 0; t < 16; ++t)
        acc += ss[g][t] * hlin[(size_t)cs[g][t] * 128 + j];
    float hl = hlin[(size_t)node * 128 + j];
    float a = aggrv ? aggrv[node] : aggrs;
    hout[(size_t)node * 128 + j] = a * acc * degree[node] + (1.f - a) * hl;
}

// ---------------------------------------------------------------------------
// Edge factors f0,f1.  One thread per edge; weights via uniform (scalar) loads.
// ---------------------------------------------------------------------------
__global__ __launch_bounds__(256) void fact_kernel(
    const float* __restrict__ m0m, const float* __restrict__ m0d,
    const float* __restrict__ m1m, const float* __restrict__ m1d,
    const int* __restrict__ col, const float* __restrict__ ab,
    const float* __restrict__ lf1w, const float* __restrict__ lf1b,
    const float* __restrict__ lf2w, const float* __restrict__ lf2b,
    float* __restrict__ f0out, float* __restrict__ f1out)
{
    const int e = blockIdx.x * 256 + threadIdx.x;
    const int i = e >> 4;
    const int c = col[e];
    float s0[17], d0[17], s1[17], d1[17], hd[17];
#pragma unroll
    for (int s = 0; s < 4; ++s) {
        float4 v;
        v = *(const float4*)(m0m + (size_t)i * 16 + s * 4);
        s0[s*4+0]=v.x; s0[s*4+1]=v.y; s0[s*4+2]=v.z; s0[s*4+3]=v.w;
        v = *(const float4*)(m0m + (size_t)c * 16 + s * 4);
        d0[s*4+0]=v.x; d0[s*4+1]=v.y; d0[s*4+2]=v.z; d0[s*4+3]=v.w;
        v = *(const float4*)(m1m + (size_t)i * 16 + s * 4);
        s1[s*4+0]=v.x; s1[s*4+1]=v.y; s1[s*4+2]=v.z; s1[s*4+3]=v.w;
        v = *(const float4*)(m1m + (size_t)c * 16 + s * 4);
        d1[s*4+0]=v.x; d1[s*4+1]=v.y; d1[s*4+2]=v.z; d1[s*4+3]=v.w;
    }
    s0[16] = m0d[i]; d0[16] = m0d[c]; s1[16] = m1d[i]; d1[16] = m1d[c];
#pragma unroll
    for (int d = 0; d < 17; ++d) hd[d] = fabsf(d0[d] - s0[d]);
#pragma unroll
    for (int d = 0; d < 17; ++d) { float abv = ab[d]; s1[d] += abv; d1[d] += abv; }
    float acc0 = lf2b[0], acc1 = lf2b[0];
    for (int k = 0; k < 16; ++k) {
        const float* __restrict__ Wk = lf1w + k * 51;
        float t0 = lf1b[k], t1 = t0;
#pragma unroll
        for (int d = 0; d < 17; ++d) {
            float w0 = Wk[d], w1 = Wk[17 + d], w2 = Wk[34 + d];
            t0 += s0[d] * w0 + d0[d] * w1 + hd[d] * w2;
            t1 += s1[d] * w0 + d1[d] * w1 + hd[d] * w2;
        }
        float lw = lf2w[k];
        float e0 = __expf(2.f * t0), e1 = __expf(2.f * t1);
        acc0 += (1.f - 2.f / (e0 + 1.f)) * lw;   // tanh(t0)
        acc1 += (1.f - 2.f / (e1 + 1.f)) * lw;   // tanh(t1)
    }
    f0out[e] = 1.f / (1.f + __expf(-acc0));
    f1out[e] = 1.f / (1.f + __expf(-acc1));
}

__global__ void f1hop_kernel(const float* __restrict__ f1, float* __restrict__ out)
{
    const int i = blockIdx.x * 256 + threadIdx.x;
    if (i >= NN) return;
    float s = 0.f;
#pragma unroll
    for (int t = 0; t < 4; ++t) {
        float4 v = *(const float4*)(f1 + (size_t)i * 16 + t * 4);
        s += v.x + v.y + v.z + v.w;
    }
    out[i] = s * (1.f / 16.f);
}

__global__ void f2hop_kernel(const float* __restrict__ f0, const float* __restrict__ f1h,
                             const int* __restrict__ col, float* __restrict__ out)
{
    const int i = blockIdx.x * 256 + threadIdx.x;
    if (i >= NN) return;
    float s = 0.f;
#pragma unroll
    for (int t = 0; t < 16; ++t) {
        int e = i * 16 + t;
        s += f0[e] * f1h[col[e]];
    }
    out[i] = s * (1.f / 16.f);
}

__global__ void leaky_kernel(float* __restrict__ h)   // in-place, float4 per thread
{
    const size_t idx = (size_t)(blockIdx.x * 256 + threadIdx.x) * 4;
    float4 v = *(const float4*)(h + idx);
    v.x = v.x > 0.f ? v.x : ALPHAC * v.x;
    v.y = v.y > 0.f ? v.y : ALPHAC * v.y;
    v.z = v.z > 0.f ? v.z : ALPHAC * v.z;
    v.w = v.w > 0.f ? v.w : ALPHAC * v.w;
    *(float4*)(h + idx) = v;
}

// ---------------------------------------------------------------------------
// Fused logits + log_softmax.  One wave per row; lanes 0..39 own classes.
// Wt is la2w transposed -> [128][40].
// ---------------------------------------------------------------------------
__global__ __launch_bounds__(256) void logits_kernel(
    const float* __restrict__ X, const float* __restrict__ Wt,
    const float* __restrict__ bias, float* __restrict__ out)
{
    __shared__ float xs[4][128];
    const int w = threadIdx.x >> 6, lane = threadIdx.x & 63;
    const int row = blockIdx.x * 4 + w;
    xs[w][lane]      = X[(size_t)row * 128 + lane];
    xs[w][lane + 64] = X[(size_t)row * 128 + 64 + lane];
    __syncthreads();
    float zval = 0.f, z = -1e30f;
    if (lane < NCLS) {
        zval = bias[lane];
#pragma unroll
        for (int k = 0; k < 128; ++k) zval += xs[w][k] * Wt[k * NCLS + lane];
        z = zval;
    }
    float m = z;
#pragma unroll
    for (int off = 32; off > 0; off >>= 1) m = fmaxf(m, __shfl_xor(m, off, 64));
    float ex = (lane < NCLS) ? __expf(zval - m) : 0.f;
    float s = ex;
#pragma unroll
    for (int off = 32; off > 0; off >>= 1) s += __shfl_xor(s, off, 64);
    if (lane < NCLS) out[(size_t)row * NCLS + lane] = zval - m - __logf(s);
}

// ---------------------------------------------------------------------------
// Prep: weight transposes + W2eff = L2F @ Ws[l][128:,:]
// ---------------------------------------------------------------------------
__global__ void transpose_lbw(const float* __restrict__ lb_w, float* __restrict__ Bt0)
{   // Bt0[k][m] = lb_w[m][k], k<256, m<128
    int idx = blockIdx.x * 256 + threadIdx.x;
    int k = idx >> 7, m = idx & 127;
    Bt0[idx] = lb_w[m * 256 + k];
}

__global__ void transpose_la2w(const float* __restrict__ la2w, float* __restrict__ Wt2)
{   // Wt2[k][c] = la2w[c][k], k<128, c<40
    int idx = blockIdx.x * 256 + threadIdx.x;
    if (idx >= 128 * NCLS) return;
    int k = idx / NCLS, c = idx % NCLS;
    Wt2[idx] = la2w[c * 128 + k];
}

__global__ void w2eff_kernel(const float* __restrict__ L2F, const float* __restrict__ Ws,
                             float* __restrict__ W2eff)
{   // W2eff[l][c][m] = sum_j L2F[c][j] * Ws[l][128+j][m]
    int idx = blockIdx.x * 256 + threadIdx.x;   // 2*40*128
    int l = idx / (NCLS * 128), r = idx % (NCLS * 128);
    int cc = r >> 7, m = r & 127;
    const float* Wl = Ws + (size_t)l * 256 * 128 + 128 * 128;
    float acc = 0.f;
    for (int jj = 0; jj < 128; ++jj) acc += L2F[cc * 128 + jj] * Wl[jj * 128 + m];
    W2eff[idx] = acc;
}

// ---------------------------------------------------------------------------
extern "C" void kernel_launch(void* const* d_in, const int* in_sizes, int n_in,
                              void* d_out, int out_size, void* d_ws, size_t ws_size,
                              hipStream_t stream)
{
    const float* x      = (const float*)d_in[0];
    const int*   edges  = (const int*)d_in[1];
    const float* degree = (const float*)d_in[2];
    const float* label  = (const float*)d_in[4];
    const float* lb_w   = (const float*)d_in[5];
    const float* lb_b   = (const float*)d_in[6];
    const float* L2F    = (const float*)d_in[7];
    const float* Ws     = (const float*)d_in[8];
    const float* w2m    = (const float*)d_in[9];
    const float* b2m    = (const float*)d_in[10];
    const float* ab     = (const float*)d_in[11];
    const float* lf1w   = (const float*)d_in[12];
    const float* lf1b   = (const float*)d_in[13];
    const float* lf2w   = (const float*)d_in[14];
    const float* lf2b   = (const float*)d_in[15];
    const float* LPW    = (const float*)d_in[16];
    const float* la2w   = (const float*)d_in[17];
    const float* la2b   = (const float*)d_in[18];
    const int* colp = edges + NEDGE;   // edges[1] = col

    float* ws = (float*)d_ws;
    size_t o = 0;
    float* bufA  = ws + o; o += (size_t)NN * 128;   // x_l / h (ping)
    float* bufL  = ws + o; o += (size_t)NN * 128;   // hlin
    float* m0mB  = ws + o; o += (size_t)NN * 16;
    float* m0dB  = ws + o; o += NN;
    float* m1mB  = ws + o; o += (size_t)NN * 16;
    float* m1dB  = ws + o; o += NN;
    float* f0B   = ws + o; o += NEDGE;
    float* f1B   = ws + o; o += NEDGE;
    float* f1hB  = ws + o; o += NN;
    float* aggrB = ws + o; o += NN;
    float* Bt0   = ws + o; o += 256 * 128;
    float* W2eff = ws + o; o += 2 * NCLS * 128;
    float* Wt2   = ws + o; o += 128 * NCLS;

    dim3 b256(256);
    // prep
    transpose_lbw<<<128, b256, 0, stream>>>(lb_w, Bt0);
    transpose_la2w<<<20, b256, 0, stream>>>(la2w, Wt2);
    w2eff_kernel<<<40, b256, 0, stream>>>(L2F, Ws, W2eff);
    // h0 = x @ lb_w^T + lb_b
    gemm128_dual<<<1563, b256, 0, stream>>>(x, 256, Bt0, nullptr, 0, nullptr, lb_b, bufA);

    // ---- layer 0 ----
    gemm128_dual<<<1563, b256, 0, stream>>>(bufA, 128, Ws, label, NCLS, W2eff, nullptr, bufL);
    gemm16<<<6250, b256, 0, stream>>>(bufA, w2m, b2m, m1mB);          // m1 = mini(x) GEMM (x = h0)
    mini2_kernel<<<6250, b256, 0, stream>>>(m1mB, colp, m1dB);
    agg_kernel<<<50000, b256, 0, stream>>>(bufL, colp, LPW, degree, nullptr, LPALPHA, bufA); // h -> bufA
    gemm16<<<6250, b256, 0, stream>>>(bufA, w2m, b2m, m0mB);          // m0 = mini(h) GEMM
    mini2_kernel<<<6250, b256, 0, stream>>>(m0mB, colp, m0dB);
    fact_kernel<<<6250, b256, 0, stream>>>(m0mB, m0dB, m1mB, m1dB, colp, ab,
                                           lf1w, lf1b, lf2w, lf2b, f0B, f1B);
    f1hop_kernel<<<391, b256, 0, stream>>>(f1B, f1hB);
    f2hop_kernel<<<391, b256, 0, stream>>>(f0B, f1hB, colp, aggrB);
    leaky_kernel<<<12500, b256, 0, stream>>>(bufA);                   // x1 = leaky(h), in place

    // ---- layer 1 (f2hop of last layer is unused -> only GEMM+agg+leaky) ----
    gemm128_dual<<<1563, b256, 0, stream>>>(bufA, 128, Ws + 256 * 128, label, NCLS,
                                            W2eff + NCLS * 128, nullptr, bufL);
    agg_kernel<<<50000, b256, 0, stream>>>(bufL, colp, LPW + NN, degree, aggrB, 0.f, bufA);
    leaky_kernel<<<12500, b256, 0, stream>>>(bufA);

    // ---- output ----
    logits_kernel<<<25000, b256, 0, stream>>>(bufA, Wt2, la2b, (float*)d_out);
}

// Round 2
// 721.758 us; speedup vs baseline: 1.2201x; 1.2201x over previous
//
#include <hip/hip_runtime.h>
#include <hip/hip_bf16.h>
#include <math.h>

#define NN 100000
#define NFEATC 256
#define NHIDC 128
#define NCLS 40
#define DEGC 16
#define NEDGE (NN*DEGC)
#define ALPHAC 0.2f
#define LPALPHA 0.5f

typedef short short8v __attribute__((ext_vector_type(8)));
typedef float f32x4 __attribute__((ext_vector_type(4)));

__device__ __forceinline__ short f2bf(float f) {
    unsigned u = __float_as_uint(f);
    u += 0x7fff + ((u >> 16) & 1);           // round-to-nearest-even
    return (short)(u >> 16);
}

// ---------------------------------------------------------------------------
// MFMA GEMM: C[NN][128] = concat_K(A1[NN][K1], A2[NN][K2]) @ concat(B1,B2) (+bias)
// B given transposed+bf16: Bt[n][k].  No LDS: each wave owns 32 rows x 128 cols;
// A-frags straight from global with f32->bf16 convert; B-frags are 16B L2 loads.
// Fragment layouts (m89-verified): A row=lane&15,k=(lane>>4)*8+j ; B col=lane&15;
// D col=lane&15,row=(lane>>4)*4+reg.
// ---------------------------------------------------------------------------
__global__ __launch_bounds__(256) void gemm128_mfma(
    const float* __restrict__ A1, int K1, const ushort* __restrict__ B1t,
    const float* __restrict__ A2, int K2, int K2p, const ushort* __restrict__ B2t,
    const float* __restrict__ bias, int leakyA, float* __restrict__ C)
{
    const int l  = threadIdx.x & 63;
    const int w  = threadIdx.x >> 6;
    const int lr = l & 15;
    const int lk = (l >> 4) << 3;
    const int row_base = blockIdx.x * 128 + w * 32;
    f32x4 acc[2][8];
#pragma unroll
    for (int mi = 0; mi < 2; ++mi)
#pragma unroll
        for (int ni = 0; ni < 8; ++ni) acc[mi][ni] = (f32x4){0.f, 0.f, 0.f, 0.f};

    const int nch1 = K1 >> 5, nch2 = K2p >> 5;
    for (int kc = 0; kc < nch1 + nch2; ++kc) {
        const float* __restrict__ A;
        const ushort* __restrict__ Bt;
        int Ast, Bst, Kr, k0;
        if (kc < nch1) { A = A1; Bt = B1t; Ast = K1; Bst = K1; Kr = K1; k0 = kc << 5; }
        else           { A = A2; Bt = B2t; Ast = K2; Bst = K2p; Kr = K2; k0 = (kc - nch1) << 5; }

        short8v afr[2];
#pragma unroll
        for (int mi = 0; mi < 2; ++mi) {
            int r = row_base + mi * 16 + lr;
            r = r < NN ? r : NN - 1;
            const int kk = k0 + lk;
            float4 v0 = make_float4(0.f, 0.f, 0.f, 0.f), v1 = v0;
            if (kk + 8 <= Kr) {                     // K2=40 splits as 32+8: always full
                const float* p = A + (size_t)r * Ast + kk;
                v0 = *(const float4*)p;
                v1 = *(const float4*)(p + 4);
            }
            if (leakyA) {
                v0.x = v0.x > 0.f ? v0.x : ALPHAC * v0.x;
                v0.y = v0.y > 0.f ? v0.y : ALPHAC * v0.y;
                v0.z = v0.z > 0.f ? v0.z : ALPHAC * v0.z;
                v0.w = v0.w > 0.f ? v0.w : ALPHAC * v0.w;
                v1.x = v1.x > 0.f ? v1.x : ALPHAC * v1.x;
                v1.y = v1.y > 0.f ? v1.y : ALPHAC * v1.y;
                v1.z = v1.z > 0.f ? v1.z : ALPHAC * v1.z;
                v1.w = v1.w > 0.f ? v1.w : ALPHAC * v1.w;
            }
            short8v a;
            a[0] = f2bf(v0.x); a[1] = f2bf(v0.y); a[2] = f2bf(v0.z); a[3] = f2bf(v0.w);
            a[4] = f2bf(v1.x); a[5] = f2bf(v1.y); a[6] = f2bf(v1.z); a[7] = f2bf(v1.w);
            afr[mi] = a;
        }
#pragma unroll
        for (int ni = 0; ni < 8; ++ni) {
            short8v b = *(const short8v*)(Bt + (size_t)(ni * 16 + lr) * Bst + k0 + lk);
#pragma unroll
            for (int mi = 0; mi < 2; ++mi)
                acc[mi][ni] = __builtin_amdgcn_mfma_f32_16x16x32_bf16(afr[mi], b, acc[mi][ni], 0, 0, 0);
        }
    }

    const int rsub = (l >> 4) << 2;
#pragma unroll
    for (int mi = 0; mi < 2; ++mi) {
        const int rb = row_base + mi * 16 + rsub;
#pragma unroll
        for (int ni = 0; ni < 8; ++ni) {
            const int cc = ni * 16 + lr;
            const float bv = bias ? bias[cc] : 0.f;
#pragma unroll
            for (int r = 0; r < 4; ++r) {
                const int rr = rb + r;
                if (rr < NN) C[(size_t)rr * 128 + cc] = acc[mi][ni][r] + bv;
            }
        }
    }
}

// ---------------------------------------------------------------------------
// Small GEMM: M[NN][16] = A[NN][128] @ W[16][128]^T + bias.  16 rows/block.
// ---------------------------------------------------------------------------
__global__ __launch_bounds__(256) void gemm16(
    const float* __restrict__ A, const float* __restrict__ W,
    const float* __restrict__ bias, float* __restrict__ Mout)
{
    __shared__ float As[16][132];
    __shared__ float Wt[128][17];
    const int n0 = blockIdx.x * 16;
    const int tid = threadIdx.x;
#pragma unroll
    for (int s = 0; s < 8; ++s) {
        int f = tid + s * 256;
        int m = f >> 7, k = f & 127;
        Wt[k][m] = W[f];
    }
#pragma unroll
    for (int s = 0; s < 2; ++s) {
        int slot = tid + s * 256;
        int r = slot >> 5, ko = (slot & 31) << 2;
        float4 v = *(const float4*)(A + (size_t)(n0 + r) * 128 + ko);
        *(float4*)&As[r][ko] = v;
    }
    __syncthreads();
    const int row = tid >> 4, m = tid & 15;
    float acc = bias[m];
#pragma unroll
    for (int k = 0; k < 128; ++k) acc += As[row][k] * Wt[k][m];
    Mout[(size_t)(n0 + row) * 16 + m] = acc;
}

// ---------------------------------------------------------------------------
// mini() second half: d2[i] = mean_e ||avg_i - m[col_e]||
// ---------------------------------------------------------------------------
__global__ __launch_bounds__(256) void mini2_kernel(
    const float* __restrict__ Mm, const int* __restrict__ col,
    float* __restrict__ d2out)
{
    __shared__ float sm[16][16][17];
    __shared__ float av[16][16];
    const int node0 = blockIdx.x * 16;
    const int tid = threadIdx.x;
    const int g = tid >> 4, j = tid & 15;
    const int node = node0 + g;
    const int c = col[node * 16 + j];
#pragma unroll
    for (int s = 0; s < 4; ++s) {
        float4 v = *(const float4*)(Mm + (size_t)c * 16 + s * 4);
        sm[g][j][s * 4 + 0] = v.x; sm[g][j][s * 4 + 1] = v.y;
        sm[g][j][s * 4 + 2] = v.z; sm[g][j][s * 4 + 3] = v.w;
    }
    __syncthreads();
    float a = 0.f;
#pragma unroll
    for (int nb = 0; nb < 16; ++nb) a += sm[g][nb][j];
    av[g][j] = a * (1.f / 16.f);
    __syncthreads();
    float dd = 1e-12f;
#pragma unroll
    for (int d = 0; d < 16; ++d) {
        float t = av[g][d] - sm[g][j][d];
        dd += t * t;
    }
    float dist = sqrtf(dd);
#pragma unroll
    for (int off = 1; off < 16; off <<= 1) dist += __shfl_xor(dist, off, 64);
    if (j == 0) d2out[node] = dist * (1.f / 16.f);
}

// ---------------------------------------------------------------------------
// Aggregation (+optional fused leaky):
// h[i] = a_i*(sum_c lpw[c]*deg[c]*hlin[c])*deg[i] + (1-a_i)*hlin[i]
// ---------------------------------------------------------------------------
__global__ __launch_bounds__(256) void agg_kernel(
    const float* __restrict__ hlin, const int* __restrict__ col,
    const float* __restrict__ lpw, const float* __restrict__ degree,
    const float* __restrict__ aggrv, const float aggrs, int do_leaky,
    float* __restrict__ hout)
{
    __shared__ int cs[2][16];
    __shared__ float ss[2][16];
    const int g = threadIdx.x >> 7;
    const int j = threadIdx.x & 127;
    const int node = blockIdx.x * 2 + g;
    if (j < 16) {
        int c = col[node * 16 + j];
        cs[g][j] = c;
        ss[g][j] = lpw[c] * degree[c];
    }
    __syncthreads();
    float acc = 0.f;
#pragma unroll
    for (int t = 0; t < 16; ++t)
        acc += ss[g][t] * hlin[(size_t)cs[g][t] * 128 + j];
    float hl = hlin[(size_t)node * 128 + j];
    float a = aggrv ? aggrv[node] : aggrs;
    float o = a * acc * degree[node] + (1.f - a) * hl;
    if (do_leaky) o = o > 0.f ? o : ALPHAC * o;
    hout[(size_t)node * 128 + j] = o;
}

// ---------------------------------------------------------------------------
// Edge factors f0,f1.
// ---------------------------------------------------------------------------
__global__ __launch_bounds__(256) void fact_kernel(
    const float* __restrict__ m0m, const float* __restrict__ m0d,
    const float* __restrict__ m1m, const float* __restrict__ m1d,
    const int* __restrict__ col, const float* __restrict__ ab,
    const float* __restrict__ lf1w, const float* __restrict__ lf1b,
    const float* __restrict__ lf2w, const float* __restrict__ lf2b,
    float* __restrict__ f0out, float* __restrict__ f1out)
{
    const int e = blockIdx.x * 256 + threadIdx.x;
    const int i = e >> 4;
    const int c = col[e];
    float s0[17], d0[17], s1[17], d1[17], hd[17];
#pragma unroll
    for (int s = 0; s < 4; ++s) {
        float4 v;
        v = *(const float4*)(m0m + (size_t)i * 16 + s * 4);
        s0[s*4+0]=v.x; s0[s*4+1]=v.y; s0[s*4+2]=v.z; s0[s*4+3]=v.w;
        v = *(const float4*)(m0m + (size_t)c * 16 + s * 4);
        d0[s*4+0]=v.x; d0[s*4+1]=v.y; d0[s*4+2]=v.z; d0[s*4+3]=v.w;
        v = *(const float4*)(m1m + (size_t)i * 16 + s * 4);
        s1[s*4+0]=v.x; s1[s*4+1]=v.y; s1[s*4+2]=v.z; s1[s*4+3]=v.w;
        v = *(const float4*)(m1m + (size_t)c * 16 + s * 4);
        d1[s*4+0]=v.x; d1[s*4+1]=v.y; d1[s*4+2]=v.z; d1[s*4+3]=v.w;
    }
    s0[16] = m0d[i]; d0[16] = m0d[c]; s1[16] = m1d[i]; d1[16] = m1d[c];
#pragma unroll
    for (int d = 0; d < 17; ++d) hd[d] = fabsf(d0[d] - s0[d]);
#pragma unroll
    for (int d = 0; d < 17; ++d) { float abv = ab[d]; s1[d] += abv; d1[d] += abv; }
    float acc0 = lf2b[0], acc1 = lf2b[0];
    for (int k = 0; k < 16; ++k) {
        const float* __restrict__ Wk = lf1w + k * 51;
        float t0 = lf1b[k], t1 = t0;
#pragma unroll
        for (int d = 0; d < 17; ++d) {
            float w0 = Wk[d], w1 = Wk[17 + d], w2 = Wk[34 + d];
            t0 += s0[d] * w0 + d0[d] * w1 + hd[d] * w2;
            t1 += s1[d] * w0 + d1[d] * w1 + hd[d] * w2;
        }
        float lw = lf2w[k];
        float e0 = __expf(2.f * t0), e1 = __expf(2.f * t1);
        acc0 += (1.f - 2.f / (e0 + 1.f)) * lw;
        acc1 += (1.f - 2.f / (e1 + 1.f)) * lw;
    }
    f0out[e] = 1.f / (1.f + __expf(-acc0));
    f1out[e] = 1.f / (1.f + __expf(-acc1));
}

__global__ void f1hop_kernel(const float* __restrict__ f1, float* __restrict__ out)
{
    const int i = blockIdx.x * 256 + threadIdx.x;
    if (i >= NN) return;
    float s = 0.f;
#pragma unroll
    for (int t = 0; t < 4; ++t) {
        float4 v = *(const float4*)(f1 + (size_t)i * 16 + t * 4);
        s += v.x + v.y + v.z + v.w;
    }
    out[i] = s * (1.f / 16.f);
}

__global__ void f2hop_kernel(const float* __restrict__ f0, const float* __restrict__ f1h,
                             const int* __restrict__ col, float* __restrict__ out)
{
    const int i = blockIdx.x * 256 + threadIdx.x;
    if (i >= NN) return;
    float s = 0.f;
#pragma unroll
    for (int t = 0; t < 16; ++t) {
        int e = i * 16 + t;
        s += f0[e] * f1h[col[e]];
    }
    out[i] = s * (1.f / 16.f);
}

// ---------------------------------------------------------------------------
// Fused logits + log_softmax.
// ---------------------------------------------------------------------------
__global__ __launch_bounds__(256) void logits_kernel(
    const float* __restrict__ X, const float* __restrict__ Wt,
    const float* __restrict__ bias, float* __restrict__ out)
{
    __shared__ float xs[4][128];
    const int w = threadIdx.x >> 6, lane = threadIdx.x & 63;
    const int row = blockIdx.x * 4 + w;
    xs[w][lane]      = X[(size_t)row * 128 + lane];
    xs[w][lane + 64] = X[(size_t)row * 128 + 64 + lane];
    __syncthreads();
    float zval = 0.f, z = -1e30f;
    if (lane < NCLS) {
        zval = bias[lane];
#pragma unroll
        for (int k = 0; k < 128; ++k) zval += xs[w][k] * Wt[k * NCLS + lane];
        z = zval;
    }
    float m = z;
#pragma unroll
    for (int off = 32; off > 0; off >>= 1) m = fmaxf(m, __shfl_xor(m, off, 64));
    float ex = (lane < NCLS) ? __expf(zval - m) : 0.f;
    float s = ex;
#pragma unroll
    for (int off = 32; off > 0; off >>= 1) s += __shfl_xor(s, off, 64);
    if (lane < NCLS) out[(size_t)row * NCLS + lane] = zval - m - __logf(s);
}

// ---------------------------------------------------------------------------
// Prep kernels: bf16 weight conversions / transposes
// ---------------------------------------------------------------------------
__global__ void cvt_lbw(const float* __restrict__ lb_w, ushort* __restrict__ Bt0)
{   // lb_w is [m=128][k=256] already n-major -> just convert. 32768 elems.
    int i = blockIdx.x * 256 + threadIdx.x;
    Bt0[i] = (ushort)f2bf(lb_w[i]);
}

__global__ void prep_wt1(const float* __restrict__ Ws, ushort* __restrict__ Wt1)
{   // Wt1[l][m][k] = Ws[l][k][m], k,m<128.  2*128*128 = 32768 elems.
    int i = blockIdx.x * 256 + threadIdx.x;
    int ll = i >> 14, r = i & 16383;
    int m = r >> 7, k = r & 127;
    Wt1[i] = (ushort)f2bf(Ws[(size_t)ll * 32768 + k * 128 + m]);
}

__global__ void prep_w2t(const float* __restrict__ L2F, const float* __restrict__ Ws,
                         ushort* __restrict__ W2t)
{   // W2t[l][m][c] (c padded to 64) = sum_j L2F[c][j]*Ws[l][128+j][m]. 2*128*64.
    int i = blockIdx.x * 256 + threadIdx.x;
    int ll = i >> 13, r = i & 8191;
    int m = r >> 6, c = r & 63;
    float acc = 0.f;
    if (c < NCLS) {
        const float* Wl = Ws + (size_t)ll * 32768 + 128 * 128;
        for (int j = 0; j < 128; ++j) acc += L2F[c * 128 + j] * Wl[j * 128 + m];
    }
    W2t[i] = (ushort)f2bf(acc);
}

__global__ void transpose_la2w(const float* __restrict__ la2w, float* __restrict__ Wt2)
{
    int idx = blockIdx.x * 256 + threadIdx.x;
    if (idx >= 128 * NCLS) return;
    int k = idx / NCLS, c = idx % NCLS;
    Wt2[idx] = la2w[c * 128 + k];
}

// ---------------------------------------------------------------------------
extern "C" void kernel_launch(void* const* d_in, const int* in_sizes, int n_in,
                              void* d_out, int out_size, void* d_ws, size_t ws_size,
                              hipStream_t stream)
{
    const float* x      = (const float*)d_in[0];
    const int*   edges  = (const int*)d_in[1];
    const float* degree = (const float*)d_in[2];
    const float* label  = (const float*)d_in[4];
    const float* lb_w   = (const float*)d_in[5];
    const float* lb_b   = (const float*)d_in[6];
    const float* L2F    = (const float*)d_in[7];
    const float* Ws     = (const float*)d_in[8];
    const float* w2m    = (const float*)d_in[9];
    const float* b2m    = (const float*)d_in[10];
    const float* ab     = (const float*)d_in[11];
    const float* lf1w   = (const float*)d_in[12];
    const float* lf1b   = (const float*)d_in[13];
    const float* lf2w   = (const float*)d_in[14];
    const float* lf2b   = (const float*)d_in[15];
    const float* LPW    = (const float*)d_in[16];
    const float* la2w   = (const float*)d_in[17];
    const float* la2b   = (const float*)d_in[18];
    const int* colp = edges + NEDGE;

    float* ws = (float*)d_ws;
    size_t o = 0;
    float* bufA  = ws + o; o += (size_t)NN * 128;
    float* bufL  = ws + o; o += (size_t)NN * 128;
    float* m0mB  = ws + o; o += (size_t)NN * 16;
    float* m0dB  = ws + o; o += NN;
    float* m1mB  = ws + o; o += (size_t)NN * 16;
    float* m1dB  = ws + o; o += NN;
    float* f0B   = ws + o; o += NEDGE;
    float* f1B   = ws + o; o += NEDGE;
    float* f1hB  = ws + o; o += NN;
    float* aggrB = ws + o; o += NN;
    float* Wt2   = ws + o; o += 128 * NCLS;
    ushort* Bt0  = (ushort*)(ws + o); o += 128 * 256 / 2;   // bf16 [128][256]
    ushort* Wt1  = (ushort*)(ws + o); o += 2 * 128 * 128 / 2;
    ushort* W2t  = (ushort*)(ws + o); o += 2 * 128 * 64 / 2;

    dim3 b256(256);
    // prep
    cvt_lbw<<<128, b256, 0, stream>>>(lb_w, Bt0);
    prep_wt1<<<128, b256, 0, stream>>>(Ws, Wt1);
    prep_w2t<<<64, b256, 0, stream>>>(L2F, Ws, W2t);
    transpose_la2w<<<20, b256, 0, stream>>>(la2w, Wt2);

    // h0 = x @ lb_w^T + lb_b
    gemm128_mfma<<<782, b256, 0, stream>>>(x, 256, Bt0, nullptr, 0, 0, nullptr,
                                           lb_b, 0, bufA);

    // ---- layer 0 ----
    gemm128_mfma<<<782, b256, 0, stream>>>(bufA, 128, Wt1, label, NCLS, 64, W2t,
                                           nullptr, 0, bufL);
    gemm16<<<6250, b256, 0, stream>>>(bufA, w2m, b2m, m1mB);
    mini2_kernel<<<6250, b256, 0, stream>>>(m1mB, colp, m1dB);
    agg_kernel<<<50000, b256, 0, stream>>>(bufL, colp, LPW, degree, nullptr, LPALPHA, 0, bufA);
    gemm16<<<6250, b256, 0, stream>>>(bufA, w2m, b2m, m0mB);
    mini2_kernel<<<6250, b256, 0, stream>>>(m0mB, colp, m0dB);
    fact_kernel<<<6250, b256, 0, stream>>>(m0mB, m0dB, m1mB, m1dB, colp, ab,
                                           lf1w, lf1b, lf2w, lf2b, f0B, f1B);
    f1hop_kernel<<<391, b256, 0, stream>>>(f1B, f1hB);
    f2hop_kernel<<<391, b256, 0, stream>>>(f0B, f1hB, colp, aggrB);

    // ---- layer 1 (aggr output unused; only GEMM+agg, leaky fused) ----
    gemm128_mfma<<<782, b256, 0, stream>>>(bufA, 128, Wt1 + 16384, label, NCLS, 64,
                                           W2t + 8192, nullptr, 1, bufL);
    agg_kernel<<<50000, b256, 0, stream>>>(bufL, colp, LPW + NN, degree, aggrB, 0.f, 1, bufA);

    // ---- output ----
    logits_kernel<<<25000, b256, 0, stream>>>(bufA, Wt2, la2b, (float*)d_out);
}

// Round 3
// 578.718 us; speedup vs baseline: 1.5217x; 1.2472x over previous
//
#include <hip/hip_runtime.h>
#include <hip/hip_bf16.h>
#include <math.h>

#define NN 100000
#define NCLS 40
#define DEGC 16
#define NEDGE (NN*DEGC)
#define ALPHAC 0.2f
#define LPALPHA 0.5f

typedef short short8v __attribute__((ext_vector_type(8)));
typedef float f32x4 __attribute__((ext_vector_type(4)));

__device__ __forceinline__ short f2bf(float f) {
    unsigned u = __float_as_uint(f);
    u += 0x7fff + ((u >> 16) & 1);           // round-to-nearest-even
    return (short)(u >> 16);
}
__device__ __forceinline__ float bf2f(ushort u) {
    return __uint_as_float(((unsigned)u) << 16);
}

// ---------------------------------------------------------------------------
// MFMA GEMM: C[NN][128](bf16) = concat_K(A1,A2) @ concat(B1,B2) (+bias)
// A bf16 (direct short8 frags) or f32 (convert). B transposed bf16 [n][k].
// No LDS: wave owns 32 rows x 128 cols. Layouts (m89): A row=lane&15,
// k=(lane>>4)*8+j ; B col=lane&15 ; D col=lane&15,row=(lane>>4)*4+reg.
// ---------------------------------------------------------------------------
template <bool ABF>
__global__ __launch_bounds__(256) void gemm128_mfma(
    const void* __restrict__ A1v, int K1, const ushort* __restrict__ B1t,
    const void* __restrict__ A2v, int K2, int K2p, const ushort* __restrict__ B2t,
    const float* __restrict__ bias, int leakyA, ushort* __restrict__ C)
{
    const int l  = threadIdx.x & 63;
    const int w  = threadIdx.x >> 6;
    const int lr = l & 15;
    const int lk = (l >> 4) << 3;
    const int row_base = blockIdx.x * 128 + w * 32;
    f32x4 acc[2][8];
#pragma unroll
    for (int mi = 0; mi < 2; ++mi)
#pragma unroll
        for (int ni = 0; ni < 8; ++ni) acc[mi][ni] = (f32x4){0.f, 0.f, 0.f, 0.f};

    const int nch1 = K1 >> 5, nch2 = K2p >> 5;
    for (int kc = 0; kc < nch1 + nch2; ++kc) {
        const void* __restrict__ Av;
        const ushort* __restrict__ Bt;
        int Ast, Bst, Kr, k0, isA1;
        if (kc < nch1) { Av = A1v; Bt = B1t; Ast = K1; Bst = K1;  Kr = K1; k0 = kc << 5; isA1 = 1; }
        else           { Av = A2v; Bt = B2t; Ast = K2; Bst = K2p; Kr = K2; k0 = (kc - nch1) << 5; isA1 = 0; }

        short8v afr[2];
#pragma unroll
        for (int mi = 0; mi < 2; ++mi) {
            int r = row_base + mi * 16 + lr;
            r = r < NN ? r : NN - 1;
            const int kk = k0 + lk;
            short8v a = (short8v){0,0,0,0,0,0,0,0};
            if (kk + 8 <= Kr) {
                if (ABF) {
                    a = *(const short8v*)((const ushort*)Av + (size_t)r * Ast + kk);
                    if (leakyA && isA1) {
#pragma unroll
                        for (int j = 0; j < 8; ++j) {
                            float f = bf2f((ushort)a[j]);
                            f = f > 0.f ? f : ALPHAC * f;
                            a[j] = f2bf(f);
                        }
                    }
                } else {
                    const float* p = (const float*)Av + (size_t)r * Ast + kk;
                    float4 v0 = *(const float4*)p;
                    float4 v1 = *(const float4*)(p + 4);
                    a[0] = f2bf(v0.x); a[1] = f2bf(v0.y); a[2] = f2bf(v0.z); a[3] = f2bf(v0.w);
                    a[4] = f2bf(v1.x); a[5] = f2bf(v1.y); a[6] = f2bf(v1.z); a[7] = f2bf(v1.w);
                }
            }
            afr[mi] = a;
        }
#pragma unroll
        for (int ni = 0; ni < 8; ++ni) {
            short8v b = *(const short8v*)(Bt + (size_t)(ni * 16 + lr) * Bst + k0 + lk);
#pragma unroll
            for (int mi = 0; mi < 2; ++mi)
                acc[mi][ni] = __builtin_amdgcn_mfma_f32_16x16x32_bf16(afr[mi], b, acc[mi][ni], 0, 0, 0);
        }
    }

    const int rsub = (l >> 4) << 2;
#pragma unroll
    for (int mi = 0; mi < 2; ++mi) {
        const int rb = row_base + mi * 16 + rsub;
#pragma unroll
        for (int ni = 0; ni < 8; ++ni) {
            const int cc = ni * 16 + lr;
            const float bv = bias ? bias[cc] : 0.f;
#pragma unroll
            for (int r = 0; r < 4; ++r) {
                const int rr = rb + r;
                if (rr < NN) C[(size_t)rr * 128 + cc] = (ushort)f2bf(acc[mi][ni][r] + bv);
            }
        }
    }
}

// ---------------------------------------------------------------------------
// Small MFMA GEMM: M[NN][16](f32) = A[NN][128](bf16) @ Wb[16][128]^T + bias.
// One wave = 16 rows (one 16x16 tile, K=128 -> 4 MFMA). Block = 64 rows.
// ---------------------------------------------------------------------------
__global__ __launch_bounds__(256) void gemm16_mfma(
    const ushort* __restrict__ A, const ushort* __restrict__ Wb,
    const float* __restrict__ bias, float* __restrict__ Mout)
{
    const int l  = threadIdx.x & 63;
    const int w  = threadIdx.x >> 6;
    const int lr = l & 15;
    const int lk = (l >> 4) << 3;
    const int n0 = blockIdx.x * 64 + w * 16;
    int ar = n0 + lr; ar = ar < NN ? ar : NN - 1;
    f32x4 acc = (f32x4){0.f, 0.f, 0.f, 0.f};
#pragma unroll
    for (int k0 = 0; k0 < 128; k0 += 32) {
        short8v a = *(const short8v*)(A + (size_t)ar * 128 + k0 + lk);
        short8v b = *(const short8v*)(Wb + (size_t)lr * 128 + k0 + lk);
        acc = __builtin_amdgcn_mfma_f32_16x16x32_bf16(a, b, acc, 0, 0, 0);
    }
    const float bv = bias[lr];
    const int rb = n0 + ((l >> 4) << 2);
#pragma unroll
    for (int r = 0; r < 4; ++r) {
        int rr = rb + r;
        if (rr < NN) Mout[(size_t)rr * 16 + lr] = acc[r] + bv;
    }
}

// ---------------------------------------------------------------------------
// mini() second half: d2[i] = mean_e ||avg_i - m[col_e]||
// ---------------------------------------------------------------------------
__global__ __launch_bounds__(256) void mini2_kernel(
    const float* __restrict__ Mm, const int* __restrict__ col,
    float* __restrict__ d2out)
{
    __shared__ float sm[16][16][17];
    __shared__ float av[16][16];
    const int node0 = blockIdx.x * 16;
    const int tid = threadIdx.x;
    const int g = tid >> 4, j = tid & 15;
    const int node = node0 + g;
    const int c = col[node * 16 + j];
#pragma unroll
    for (int s = 0; s < 4; ++s) {
        float4 v = *(const float4*)(Mm + (size_t)c * 16 + s * 4);
        sm[g][j][s * 4 + 0] = v.x; sm[g][j][s * 4 + 1] = v.y;
        sm[g][j][s * 4 + 2] = v.z; sm[g][j][s * 4 + 3] = v.w;
    }
    __syncthreads();
    float a = 0.f;
#pragma unroll
    for (int nb = 0; nb < 16; ++nb) a += sm[g][nb][j];
    av[g][j] = a * (1.f / 16.f);
    __syncthreads();
    float dd = 1e-12f;
#pragma unroll
    for (int d = 0; d < 16; ++d) {
        float t = av[g][d] - sm[g][j][d];
        dd += t * t;
    }
    float dist = sqrtf(dd);
#pragma unroll
    for (int off = 1; off < 16; off <<= 1) dist += __shfl_xor(dist, off, 64);
    if (j == 0) d2out[node] = dist * (1.f / 16.f);
}

// ---------------------------------------------------------------------------
// Aggregation, bf16 rows: one wave per node, lane covers 2 cols (uint load).
// h[i] = a_i*(sum_c lpw[c]*deg[c]*h[c])*deg[i] + (1-a_i)*h[i]  (+opt leaky)
// ---------------------------------------------------------------------------
__global__ __launch_bounds__(256) void agg_bf16(
    const ushort* __restrict__ hlin, const int* __restrict__ col,
    const float* __restrict__ lpw, const float* __restrict__ degree,
    const float* __restrict__ aggrv, const float aggrs, int do_leaky,
    ushort* __restrict__ hout)
{
    const int lane = threadIdx.x & 63;
    const int node = blockIdx.x * 4 + (threadIdx.x >> 6);
    int cl = 0; float sl = 0.f;
    if (lane < 16) {
        cl = col[node * 16 + lane];
        sl = lpw[cl] * degree[cl];
    }
    float ax = 0.f, ay = 0.f;
#pragma unroll
    for (int t = 0; t < 16; ++t) {
        const int ct = __shfl(cl, t, 64);
        const float st = __shfl(sl, t, 64);
        const unsigned u = *(const unsigned*)(hlin + (size_t)ct * 128 + lane * 2);
        ax += st * bf2f((ushort)(u & 0xffff));
        ay += st * bf2f((ushort)(u >> 16));
    }
    const unsigned us = *(const unsigned*)(hlin + (size_t)node * 128 + lane * 2);
    const float a = aggrv ? aggrv[node] : aggrs;
    const float d = degree[node];
    float ox = a * ax * d + (1.f - a) * bf2f((ushort)(us & 0xffff));
    float oy = a * ay * d + (1.f - a) * bf2f((ushort)(us >> 16));
    if (do_leaky) {
        ox = ox > 0.f ? ox : ALPHAC * ox;
        oy = oy > 0.f ? oy : ALPHAC * oy;
    }
    const unsigned uo = (unsigned)(ushort)f2bf(ox) | ((unsigned)(ushort)f2bf(oy) << 16);
    *(unsigned*)(hout + (size_t)node * 128 + lane * 2) = uo;
}

// ---------------------------------------------------------------------------
// Edge factors f0 (per-edge) + fused f1hop (per-node mean of f1).
// ---------------------------------------------------------------------------
__global__ __launch_bounds__(256) void fact_kernel(
    const float* __restrict__ m0m, const float* __restrict__ m0d,
    const float* __restrict__ m1m, const float* __restrict__ m1d,
    const int* __restrict__ col, const float* __restrict__ ab,
    const float* __restrict__ lf1w, const float* __restrict__ lf1b,
    const float* __restrict__ lf2w, const float* __restrict__ lf2b,
    float* __restrict__ f0out, float* __restrict__ f1hout)
{
    const int e = blockIdx.x * 256 + threadIdx.x;
    const int i = e >> 4;
    const int c = col[e];
    float s0[17], d0[17], s1[17], d1[17], hd[17];
#pragma unroll
    for (int s = 0; s < 4; ++s) {
        float4 v;
        v = *(const float4*)(m0m + (size_t)i * 16 + s * 4);
        s0[s*4+0]=v.x; s0[s*4+1]=v.y; s0[s*4+2]=v.z; s0[s*4+3]=v.w;
        v = *(const float4*)(m0m + (size_t)c * 16 + s * 4);
        d0[s*4+0]=v.x; d0[s*4+1]=v.y; d0[s*4+2]=v.z; d0[s*4+3]=v.w;
        v = *(const float4*)(m1m + (size_t)i * 16 + s * 4);
        s1[s*4+0]=v.x; s1[s*4+1]=v.y; s1[s*4+2]=v.z; s1[s*4+3]=v.w;
        v = *(const float4*)(m1m + (size_t)c * 16 + s * 4);
        d1[s*4+0]=v.x; d1[s*4+1]=v.y; d1[s*4+2]=v.z; d1[s*4+3]=v.w;
    }
    s0[16] = m0d[i]; d0[16] = m0d[c]; s1[16] = m1d[i]; d1[16] = m1d[c];
#pragma unroll
    for (int d = 0; d < 17; ++d) hd[d] = fabsf(d0[d] - s0[d]);
#pragma unroll
    for (int d = 0; d < 17; ++d) { float abv = ab[d]; s1[d] += abv; d1[d] += abv; }
    float acc0 = lf2b[0], acc1 = lf2b[0];
    for (int k = 0; k < 16; ++k) {
        const float* __restrict__ Wk = lf1w + k * 51;
        float t0 = lf1b[k], t1 = t0;
#pragma unroll
        for (int d = 0; d < 17; ++d) {
            float w0 = Wk[d], w1 = Wk[17 + d], w2 = Wk[34 + d];
            t0 += s0[d] * w0 + d0[d] * w1 + hd[d] * w2;
            t1 += s1[d] * w0 + d1[d] * w1 + hd[d] * w2;
        }
        float lw = lf2w[k];
        float e0 = __expf(2.f * t0), e1 = __expf(2.f * t1);
        acc0 += (1.f - 2.f / (e0 + 1.f)) * lw;
        acc1 += (1.f - 2.f / (e1 + 1.f)) * lw;
    }
    f0out[e] = 1.f / (1.f + __expf(-acc0));
    float f1 = 1.f / (1.f + __expf(-acc1));
#pragma unroll
    for (int off = 1; off < 16; off <<= 1) f1 += __shfl_xor(f1, off, 64);
    if ((threadIdx.x & 15) == 0) f1hout[i] = f1 * (1.f / 16.f);
}

__global__ void f2hop_kernel(const float* __restrict__ f0, const float* __restrict__ f1h,
                             const int* __restrict__ col, float* __restrict__ out)
{
    const int i = blockIdx.x * 256 + threadIdx.x;
    if (i >= NN) return;
    float s = 0.f;
#pragma unroll
    for (int t = 0; t < 16; ++t) {
        int e = i * 16 + t;
        s += f0[e] * f1h[col[e]];
    }
    out[i] = s * (1.f / 16.f);
}

// ---------------------------------------------------------------------------
// Fused logits + log_softmax (X bf16).
// ---------------------------------------------------------------------------
__global__ __launch_bounds__(256) void logits_kernel(
    const ushort* __restrict__ X, const float* __restrict__ Wt,
    const float* __restrict__ bias, float* __restrict__ out)
{
    __shared__ float xs[4][128];
    const int w = threadIdx.x >> 6, lane = threadIdx.x & 63;
    const int row = blockIdx.x * 4 + w;
    const unsigned u = *(const unsigned*)(X + (size_t)row * 128 + lane * 2);
    xs[w][lane * 2]     = bf2f((ushort)(u & 0xffff));
    xs[w][lane * 2 + 1] = bf2f((ushort)(u >> 16));
    __syncthreads();
    float zval = 0.f, z = -1e30f;
    if (lane < NCLS) {
        zval = bias[lane];
#pragma unroll
        for (int k = 0; k < 128; ++k) zval += xs[w][k] * Wt[k * NCLS + lane];
        z = zval;
    }
    float m = z;
#pragma unroll
    for (int off = 32; off > 0; off >>= 1) m = fmaxf(m, __shfl_xor(m, off, 64));
    float ex = (lane < NCLS) ? __expf(zval - m) : 0.f;
    float s = ex;
#pragma unroll
    for (int off = 32; off > 0; off >>= 1) s += __shfl_xor(s, off, 64);
    if (lane < NCLS) out[(size_t)row * NCLS + lane] = zval - m - __logf(s);
}

// ---------------------------------------------------------------------------
// Prep kernels
// ---------------------------------------------------------------------------
__global__ void cvt_bf16(const float* __restrict__ src, ushort* __restrict__ dst, int n)
{
    int i = blockIdx.x * 256 + threadIdx.x;
    if (i < n) dst[i] = (ushort)f2bf(src[i]);
}

__global__ void prep_wt1(const float* __restrict__ Ws, ushort* __restrict__ Wt1)
{   // Wt1[l][m][k] = Ws[l][k][m], k,m<128.
    int i = blockIdx.x * 256 + threadIdx.x;
    int ll = i >> 14, r = i & 16383;
    int m = r >> 7, k = r & 127;
    Wt1[i] = (ushort)f2bf(Ws[(size_t)ll * 32768 + k * 128 + m]);
}

__global__ void prep_w2t(const float* __restrict__ L2F, const float* __restrict__ Ws,
                         ushort* __restrict__ W2t)
{   // W2t[l][m][c] (c padded to 64) = sum_j L2F[c][j]*Ws[l][128+j][m].
    int i = blockIdx.x * 256 + threadIdx.x;
    int ll = i >> 13, r = i & 8191;
    int m = r >> 6, c = r & 63;
    float acc = 0.f;
    if (c < NCLS) {
        const float* Wl = Ws + (size_t)ll * 32768 + 128 * 128;
        for (int j = 0; j < 128; ++j) acc += L2F[c * 128 + j] * Wl[j * 128 + m];
    }
    W2t[i] = (ushort)f2bf(acc);
}

__global__ void transpose_la2w(const float* __restrict__ la2w, float* __restrict__ Wt2)
{
    int idx = blockIdx.x * 256 + threadIdx.x;
    if (idx >= 128 * NCLS) return;
    int k = idx / NCLS, c = idx % NCLS;
    Wt2[idx] = la2w[c * 128 + k];
}

// ---------------------------------------------------------------------------
extern "C" void kernel_launch(void* const* d_in, const int* in_sizes, int n_in,
                              void* d_out, int out_size, void* d_ws, size_t ws_size,
                              hipStream_t stream)
{
    const float* x      = (const float*)d_in[0];
    const int*   edges  = (const int*)d_in[1];
    const float* degree = (const float*)d_in[2];
    const float* label  = (const float*)d_in[4];
    const float* lb_w   = (const float*)d_in[5];
    const float* lb_b   = (const float*)d_in[6];
    const float* L2F    = (const float*)d_in[7];
    const float* Ws     = (const float*)d_in[8];
    const float* w2m    = (const float*)d_in[9];
    const float* b2m    = (const float*)d_in[10];
    const float* ab     = (const float*)d_in[11];
    const float* lf1w   = (const float*)d_in[12];
    const float* lf1b   = (const float*)d_in[13];
    const float* lf2w   = (const float*)d_in[14];
    const float* lf2b   = (const float*)d_in[15];
    const float* LPW    = (const float*)d_in[16];
    const float* la2w   = (const float*)d_in[17];
    const float* la2b   = (const float*)d_in[18];
    const int* colp = edges + NEDGE;

    float* ws = (float*)d_ws;
    size_t o = 0;
    float* m0mB  = ws + o; o += (size_t)NN * 16;
    float* m0dB  = ws + o; o += NN;
    float* m1mB  = ws + o; o += (size_t)NN * 16;
    float* m1dB  = ws + o; o += NN;
    float* f0B   = ws + o; o += NEDGE;
    float* f1hB  = ws + o; o += NN;
    float* aggrB = ws + o; o += NN;
    float* Wt2   = ws + o; o += 128 * NCLS;
    ushort* bufA = (ushort*)(ws + o); o += (size_t)NN * 128 / 2;   // bf16 N x 128
    ushort* bufL = (ushort*)(ws + o); o += (size_t)NN * 128 / 2;
    ushort* labB = (ushort*)(ws + o); o += (size_t)NN * NCLS / 2;  // bf16 N x 40
    ushort* Bt0  = (ushort*)(ws + o); o += 128 * 256 / 2;
    ushort* Wt1  = (ushort*)(ws + o); o += 2 * 128 * 128 / 2;
    ushort* W2t  = (ushort*)(ws + o); o += 2 * 128 * 64 / 2;
    ushort* W2mB = (ushort*)(ws + o); o += 16 * 128 / 2;

    dim3 b256(256);
    // prep
    cvt_bf16<<<128, b256, 0, stream>>>(lb_w, Bt0, 128 * 256);
    prep_wt1<<<128, b256, 0, stream>>>(Ws, Wt1);
    prep_w2t<<<64, b256, 0, stream>>>(L2F, Ws, W2t);
    transpose_la2w<<<20, b256, 0, stream>>>(la2w, Wt2);
    cvt_bf16<<<8, b256, 0, stream>>>(w2m, W2mB, 16 * 128);
    cvt_bf16<<<(NN * NCLS + 255) / 256, b256, 0, stream>>>(label, labB, NN * NCLS);

    // h0 = x @ lb_w^T + lb_b   (A f32)
    gemm128_mfma<false><<<782, b256, 0, stream>>>(x, 256, Bt0, nullptr, 0, 0, nullptr,
                                                  lb_b, 0, bufA);

    // ---- layer 0 ----
    gemm128_mfma<true><<<782, b256, 0, stream>>>(bufA, 128, Wt1, labB, NCLS, 64, W2t,
                                                 nullptr, 0, bufL);
    gemm16_mfma<<<1563, b256, 0, stream>>>(bufA, W2mB, b2m, m1mB);
    mini2_kernel<<<6250, b256, 0, stream>>>(m1mB, colp, m1dB);
    agg_bf16<<<25000, b256, 0, stream>>>(bufL, colp, LPW, degree, nullptr, LPALPHA, 0, bufA);
    gemm16_mfma<<<1563, b256, 0, stream>>>(bufA, W2mB, b2m, m0mB);
    mini2_kernel<<<6250, b256, 0, stream>>>(m0mB, colp, m0dB);
    fact_kernel<<<6250, b256, 0, stream>>>(m0mB, m0dB, m1mB, m1dB, colp, ab,
                                           lf1w, lf1b, lf2w, lf2b, f0B, f1hB);
    f2hop_kernel<<<391, b256, 0, stream>>>(f0B, f1hB, colp, aggrB);

    // ---- layer 1 (aggr output unused; leaky fused into GEMM-A load & agg out) ----
    gemm128_mfma<true><<<782, b256, 0, stream>>>(bufA, 128, Wt1 + 16384, labB, NCLS, 64,
                                                 W2t + 8192, nullptr, 1, bufL);
    agg_bf16<<<25000, b256, 0, stream>>>(bufL, colp, LPW + NN, degree, aggrB, 0.f, 1, bufA);

    // ---- output ----
    logits_kernel<<<25000, b256, 0, stream>>>(bufA, Wt2, la2b, (float*)d_out);
}